// Round 4
// baseline (742.902 us; speedup 1.0000x reference)
//
#include <hip/hip_runtime.h>

// ---------------------------------------------------------------------------
// Fused MHA: qkv = x@Wqkv+b ; causal attention ; out = attn@Wproj+b
// B=4, T=2048, C=2048, H=16, D=128. fp32 in/out, bf16 MFMA internally.
// ---------------------------------------------------------------------------

typedef __bf16 bf16;
typedef __bf16 bf16x8 __attribute__((ext_vector_type(8)));
typedef __bf16 bf16x4 __attribute__((ext_vector_type(4)));
typedef float f32x4 __attribute__((ext_vector_type(4)));

__device__ __forceinline__ void gload_lds16(const void* g, void* l) {
  __builtin_amdgcn_global_load_lds(
      (const __attribute__((address_space(1))) void*)g,
      (__attribute__((address_space(3))) void*)l, 16, 0, 0);
}

// ---------------------------------------------------------------------------
// cast fp32 -> bf16, 8 elems/thread
__global__ __launch_bounds__(256) void cast_f32_bf16(
    const float* __restrict__ in, bf16* __restrict__ out, int n8) {
  int i = blockIdx.x * 256 + threadIdx.x;
  if (i >= n8) return;
  const float4* p = (const float4*)in + (size_t)i * 2;
  float4 a = p[0], b = p[1];
  bf16x8 o8 = {(bf16)a.x, (bf16)a.y, (bf16)a.z, (bf16)a.w,
               (bf16)b.x, (bf16)b.y, (bf16)b.z, (bf16)b.w};
  *(bf16x8*)(out + (size_t)i * 8) = o8;
}

// ---------------------------------------------------------------------------
// W [R][C] fp32  ->  WT [C][R] bf16   (32x32 LDS tile transpose)
__global__ __launch_bounds__(256) void transpose_cast(
    const float* __restrict__ in, bf16* __restrict__ out, int R, int C) {
  __shared__ bf16 tile[32][33];
  const int r0 = blockIdx.y * 32, c0 = blockIdx.x * 32;
  const int tid = threadIdx.x;
  const int c = tid & 31, r = tid >> 5;
#pragma unroll
  for (int rr = r; rr < 32; rr += 8)
    tile[rr][c] = (bf16)in[(size_t)(r0 + rr) * C + c0 + c];
  __syncthreads();
  const int oc = tid >> 3;           // out row within tile (0..31)
  const int ok = (tid & 7) * 4;      // out col chunk
  bf16x4 v;
#pragma unroll
  for (int j = 0; j < 4; ++j) v[j] = tile[ok + j][oc];
  *(bf16x4*)&out[(size_t)(c0 + oc) * R + r0 + ok] = v;
}

// ---------------------------------------------------------------------------
// 256x256 8-phase GEMM (m201 structure, plain HIP): C = A @ BT^T + bias.
// A [M][K] bf16 row-major, BT [N][K] bf16. 512 thr = 8 waves (2M x 4N),
// BK=64 as 2 K-halves of 32. LDS 128 KiB: [2 dbuf][2 kh][256 rows][32 elem]
// per operand, 64B rows, st_16x32 swizzle (byte bit5 ^= row bit3), applied
// as pre-XOR'd global source + XOR'd ds_read (rule #21).
// Per K-tile: 4 phases {stage 1 half-tile of t+1; ds_read; barrier;
// lgkmcnt(0); setprio+16 MFMA; counted vmcnt; barrier}. vmcnt(4) at ph1/ph3
// (2 half-tiles left in flight), vmcnt(0) only at tail. XCD-swizzled grid.
// EPI 0: scatter Q [BH][T][D], K [BH][T][D], V^T [BH][D][T]; EPI 1: fp32+bias.
template <int EPI>
__global__ __launch_bounds__(512, 2) void gemm256(
    const bf16* __restrict__ A, const bf16* __restrict__ BT,
    const float* __restrict__ bias, int M, int N, int K,
    float* __restrict__ outf, bf16* __restrict__ qb, bf16* __restrict__ kb,
    bf16* __restrict__ vtb) {
  __shared__ bf16 As[2][2][256 * 32];  // 64 KB
  __shared__ bf16 Bs[2][2][256 * 32];  // 64 KB
  const int tid = threadIdx.x;
  const int lane = tid & 63, w = tid >> 6;
  const int wm = w >> 2, wn = w & 3;
  const int lr = lane & 15, lg = lane >> 4;

  // bijective XCD swizzle (gridDim.x % 8 == 0 for both instantiations)
  const int nwg = gridDim.x, cpx = nwg >> 3;
  const int swz = (blockIdx.x & 7) * cpx + (blockIdx.x >> 3);
  const int ntx = N >> 8;  // tiles along N
  const int m0 = (swz / ntx) * 256, n0 = (swz % ntx) * 256;

  // stage one 16KB half-tile (op, kh) of K-tile kt into dbuf d.
  // dest linear; source col pre-XOR'd by row-bit3 (st_16x32 both-sides).
  auto STAGE_H = [&](int d, int skh, int sisB, int kt) {
    const bf16* src = sisB ? BT : A;
    const int r0 = sisB ? n0 : m0;
    bf16* lb = sisB ? &Bs[d][skh][0] : &As[d][skh][0];
#pragma unroll
    for (int c = 0; c < 2; ++c) {
      const int chunk = w * 2 + c;                    // 0..15 (1KB chunks)
      const int row = chunk * 16 + (lane >> 2);       // 0..255
      const int col = ((lane & 3) * 8) ^ (((row >> 3) & 1) << 4);
      gload_lds16(src + (size_t)(r0 + row) * K + kt * 64 + skh * 32 + col,
                  (char*)lb + chunk * 1024);
    }
  };
  // fragment reads (swizzled): logical (row, lg*8..+7) of K-half kh
  auto LDA = [&](int d, int kh, int mi) -> bf16x8 {
    const int row = wm * 128 + mi * 16 + lr;
    return *(const bf16x8*)((const char*)&As[d][kh][0] +
                            ((row * 64 + lg * 16) ^ ((lr >> 3) << 5)));
  };
  auto LDB = [&](int d, int kh, int ni) -> bf16x8 {
    const int row = wn * 64 + ni * 16 + lr;
    return *(const bf16x8*)((const char*)&Bs[d][kh][0] +
                            ((row * 64 + lg * 16) ^ ((lr >> 3) << 5)));
  };

  f32x4 acc[8][4] = {};
  bf16x8 af[8];
  const int NT = K >> 6;

  // prologue: stage all 4 half-tiles of tile 0; guarantee Ak0,Bk0 landed
  STAGE_H(0, 0, 0, 0);
  STAGE_H(0, 0, 1, 0);
  STAGE_H(0, 1, 0, 0);
  STAGE_H(0, 1, 1, 0);
  asm volatile("s_waitcnt vmcnt(4)" ::: "memory");
  __builtin_amdgcn_s_barrier();

  for (int t = 0; t < NT; ++t) {
    const int d = t & 1;
    const bool pf = (t + 1 < NT);
#pragma unroll
    for (int ph = 0; ph < 4; ++ph) {
      const int kh = ph >> 1, part = ph & 1;
      if (pf) STAGE_H(d ^ 1, ph >> 1, ph & 1, t + 1);
      bf16x8 b0 = LDB(d, kh, part * 2);
      bf16x8 b1 = LDB(d, kh, part * 2 + 1);
      if (part == 0) {
#pragma unroll
        for (int mi = 0; mi < 8; ++mi) af[mi] = LDA(d, kh, mi);
      }
      __builtin_amdgcn_s_barrier();
      asm volatile("s_waitcnt lgkmcnt(0)" ::: "memory");
      __builtin_amdgcn_sched_barrier(0);
      __builtin_amdgcn_s_setprio(1);
#pragma unroll
      for (int mi = 0; mi < 8; ++mi) {
        acc[mi][part * 2] = __builtin_amdgcn_mfma_f32_16x16x32_bf16(
            af[mi], b0, acc[mi][part * 2], 0, 0, 0);
        acc[mi][part * 2 + 1] = __builtin_amdgcn_mfma_f32_16x16x32_bf16(
            af[mi], b1, acc[mi][part * 2 + 1], 0, 0, 0);
      }
      __builtin_amdgcn_s_setprio(0);
      __builtin_amdgcn_sched_barrier(0);
      if (ph == 1) {  // need this tile's Ak1,Bk1 before ph2 reads
        if (pf) asm volatile("s_waitcnt vmcnt(4)" ::: "memory");
        else    asm volatile("s_waitcnt vmcnt(0)" ::: "memory");
      } else if (ph == 3 && pf) {  // need t+1's Ak0,Bk0 before its ph0
        asm volatile("s_waitcnt vmcnt(4)" ::: "memory");
      }
      __builtin_amdgcn_s_barrier();
    }
  }

  // epilogue: C/D layout col=lane&15, row=(lane>>4)*4+r  [m89/m91]
#pragma unroll
  for (int mi = 0; mi < 8; ++mi) {
    const int mbase = m0 + wm * 128 + mi * 16 + lg * 4;
#pragma unroll
    for (int ni = 0; ni < 4; ++ni) {
      const int n = n0 + wn * 64 + ni * 16 + lr;
      const float bv = bias[n];
      if (EPI == 1) {
#pragma unroll
        for (int r = 0; r < 4; ++r)
          outf[(size_t)(mbase + r) * N + n] = acc[mi][ni][r] + bv;
      } else {
        const int which = n >> 11;           // 0=q 1=k 2=v
        const int cc = n & 2047, h = cc >> 7, dd = cc & 127;
        const int b = mbase >> 11, t0 = mbase & 2047;  // 4-row group never
        const int bh = b * 16 + h;                     // crosses b boundary
        if (which == 2) {
          bf16x4 pk;
#pragma unroll
          for (int r = 0; r < 4; ++r) pk[r] = (bf16)(acc[mi][ni][r] + bv);
          *(bf16x4*)&vtb[((size_t)bh * 128 + dd) * 2048 + t0] = pk;
        } else {
          bf16* dst = (which == 0) ? qb : kb;
#pragma unroll
          for (int r = 0; r < 4; ++r)
            dst[((size_t)bh * 2048 + t0 + r) * 128 + dd] =
                (bf16)(acc[mi][ni][r] + bv);
        }
      }
    }
  }
}

// ---------------------------------------------------------------------------
// Flash attention, causal. grid = (T/128, B*H). 4 waves; each wave owns two
// 16-row q-groups sharing each staged K/V tile. (unchanged from round 2/3)
__global__ __launch_bounds__(256) void attn_kernel(
    const bf16* __restrict__ qb, const bf16* __restrict__ kb,
    const bf16* __restrict__ vtb, bf16* __restrict__ ob) {
  __shared__ bf16 Ks[2][64 * 128];  // 2 x 16 KB, swizzled
  __shared__ bf16 Vs[2][128 * 64];  // 2 x 16 KB, swizzled
  __shared__ bf16 Ps[4][16][72];    // per-wave P, pad 64->72
  const int tid = threadIdx.x, lane = tid & 63, w = tid >> 6;
  const int qt = (gridDim.x - 1) - blockIdx.x;  // big causal blocks first
  const int bh = blockIdx.y;
  const int lr = lane & 15, lg = lane >> 4;
  const int q0 = qt * 128;
  const size_t base = (size_t)bh * (2048 * 128);
  const int rswz = (lr & 7) << 3;  // read-side XOR (element domain)

  // hoist Q frags; fold (1/sqrt(D))*log2(e) so softmax runs in exp2 domain
  const float qscale = 0.08838834764831845f * 1.4426950408889634f;
  bf16x8 qf[2][4];
#pragma unroll
  for (int g = 0; g < 2; ++g) {
    const bf16* qp =
        qb + base + (size_t)(q0 + g * 64 + w * 16 + lr) * 128 + lg * 8;
#pragma unroll
    for (int kk = 0; kk < 4; ++kk) {
      bf16x8 t = *(const bf16x8*)(qp + kk * 32);
#pragma unroll
      for (int e = 0; e < 8; ++e) t[e] = (bf16)((float)t[e] * qscale);
      qf[g][kk] = t;
    }
  }

  f32x4 o[2][8] = {};
  float mst[2][4], lst[2][4];
#pragma unroll
  for (int g = 0; g < 2; ++g)
#pragma unroll
    for (int r = 0; r < 4; ++r) { mst[g][r] = -1e30f; lst[g][r] = 0.f; }

  // stage tile kt into buffer bsel (8 gload_lds / wave)
  auto STAGE = [&](int bsel, int kt) {
#pragma unroll
    for (int c = 0; c < 4; ++c) {
      const int L = w * 1024 + c * 4096 + lane * 16;  // lds byte offset
      {  // K tile rows 256B; pre-XOR source col so swizzled-read is logical
        const int row = L >> 8, ce = (L & 255) >> 1;
        gload_lds16(kb + base + (size_t)(kt * 64 + row) * 128 +
                        (ce ^ ((row & 7) << 3)),
                    (char*)Ks[bsel] + w * 1024 + c * 4096);
      }
      {  // V^T tile rows 128B
        const int d = L >> 7, ce = (L & 127) >> 1;
        gload_lds16(vtb + base + (size_t)d * 2048 + kt * 64 +
                        (ce ^ ((d & 7) << 3)),
                    (char*)Vs[bsel] + w * 1024 + c * 4096);
      }
    }
  };

  const int ntiles = 2 * qt + 2;
  STAGE(0, 0);
  for (int kt = 0; kt < ntiles; ++kt) {
    const int cur = kt & 1;
    if (kt + 1 < ntiles) {
      STAGE(cur ^ 1, kt + 1);
      asm volatile("s_waitcnt vmcnt(8)" ::: "memory");  // cur tile done,
    } else {                                            // next stays in flight
      asm volatile("s_waitcnt vmcnt(0)" ::: "memory");
    }
    __builtin_amdgcn_s_barrier();
    __builtin_amdgcn_sched_barrier(0);

    const bf16* Kc = Ks[cur];
    const bf16* Vc = Vs[cur];
#pragma unroll
    for (int g = 0; g < 2; ++g) {
      if (kt > 2 * qt + g) continue;  // uniform branch
      const bool diag = (kt == 2 * qt + g);

      // S = Q K^T : B-frag col=lr -> K row j*16+lr (swizzled read)
      f32x4 s[4] = {};
      __builtin_amdgcn_s_setprio(1);
#pragma unroll
      for (int kk = 0; kk < 4; ++kk)
#pragma unroll
        for (int j = 0; j < 4; ++j) {
          const bf16x8 kf = *(const bf16x8*)&Kc[(j * 16 + lr) * 128 +
                                               ((kk * 32 + lg * 8) ^ rswz)];
          s[j] = __builtin_amdgcn_mfma_f32_16x16x32_bf16(qf[g][kk], kf, s[j],
                                                         0, 0, 0);
        }
      __builtin_amdgcn_s_setprio(0);

      if (diag) {
#pragma unroll
        for (int j = 0; j < 4; ++j)
#pragma unroll
          for (int r = 0; r < 4; ++r) {
            const int qq = w * 16 + lg * 4 + r;
            if (j * 16 + lr > qq) s[j][r] = -1e30f;
          }
      }

      // online softmax (exp2 domain); q-row = 16 lanes of one lg-group
      float pmax[4];
#pragma unroll
      for (int r = 0; r < 4; ++r) {
        float pm = fmaxf(fmaxf(s[0][r], s[1][r]), fmaxf(s[2][r], s[3][r]));
        pm = fmaxf(pm, __shfl_xor(pm, 1, 16));
        pm = fmaxf(pm, __shfl_xor(pm, 2, 16));
        pm = fmaxf(pm, __shfl_xor(pm, 4, 16));
        pm = fmaxf(pm, __shfl_xor(pm, 8, 16));
        pmax[r] = pm;
      }
      bool need = false;
#pragma unroll
      for (int r = 0; r < 4; ++r) need |= (pmax[r] > mst[g][r]);
      if (__any(need)) {  // skip rescale pass when no row's max grew (exact)
#pragma unroll
        for (int r = 0; r < 4; ++r) {
          const float mnew = fmaxf(mst[g][r], pmax[r]);
          const float alpha = __builtin_amdgcn_exp2f(mst[g][r] - mnew);
          mst[g][r] = mnew;
          lst[g][r] *= alpha;
#pragma unroll
          for (int n = 0; n < 8; ++n) o[g][n][r] *= alpha;
        }
      }
      float rsum[4] = {0.f, 0.f, 0.f, 0.f};
#pragma unroll
      for (int j = 0; j < 4; ++j)
#pragma unroll
        for (int r = 0; r < 4; ++r) {
          const float p = __builtin_amdgcn_exp2f(s[j][r] - mst[g][r]);
          rsum[r] += p;
          Ps[w][lg * 4 + r][j * 16 + lr] = (bf16)p;
        }
#pragma unroll
      for (int r = 0; r < 4; ++r) {
        rsum[r] += __shfl_xor(rsum[r], 1, 16);
        rsum[r] += __shfl_xor(rsum[r], 2, 16);
        rsum[r] += __shfl_xor(rsum[r], 4, 16);
        rsum[r] += __shfl_xor(rsum[r], 8, 16);
        lst[g][r] += rsum[r];
      }

      // P (via per-wave LDS, within-wave ordering) @ V (swizzled read)
      bf16x8 pf[2];
#pragma unroll
      for (int kk = 0; kk < 2; ++kk)
        pf[kk] = *(const bf16x8*)&Ps[w][lr][kk * 32 + lg * 8];
      __builtin_amdgcn_s_setprio(1);
#pragma unroll
      for (int n = 0; n < 8; ++n)
#pragma unroll
        for (int kk = 0; kk < 2; ++kk) {
          const bf16x8 vf = *(const bf16x8*)&Vc[(n * 16 + lr) * 64 +
                                               ((kk * 32 + lg * 8) ^ rswz)];
          o[g][n] = __builtin_amdgcn_mfma_f32_16x16x32_bf16(pf[kk], vf,
                                                            o[g][n], 0, 0, 0);
        }
      __builtin_amdgcn_s_setprio(0);
    }
    __builtin_amdgcn_sched_barrier(0);
    __builtin_amdgcn_s_barrier();  // all reads of buf cur done before next
    __builtin_amdgcn_sched_barrier(0);  // STAGE overwrites it
  }

  // write attn-out as bf16 [B*T][C]
  const int b = bh >> 4, h = bh & 15;
#pragma unroll
  for (int g = 0; g < 2; ++g)
#pragma unroll
    for (int r = 0; r < 4; ++r) {
      const float inv = 1.0f / lst[g][r];
      const int t = q0 + g * 64 + w * 16 + lg * 4 + r;
      bf16* dst = ob + ((size_t)(b * 2048 + t)) * 2048 + h * 128;
#pragma unroll
      for (int n = 0; n < 8; ++n) dst[n * 16 + lr] = (bf16)(o[g][n][r] * inv);
    }
}

// ---------------------------------------------------------------------------
extern "C" void kernel_launch(void* const* d_in, const int* in_sizes, int n_in,
                              void* d_out, int out_size, void* d_ws,
                              size_t ws_size, hipStream_t stream) {
  const float* x = (const float*)d_in[0];      // [4,2048,2048]
  const float* Wqkv = (const float*)d_in[1];   // [2048,6144]
  const float* bqkv = (const float*)d_in[2];   // [6144]
  const float* Wproj = (const float*)d_in[3];  // [2048,2048]
  const float* bproj = (const float*)d_in[4];  // [2048]
  float* out = (float*)d_out;                  // [8192,2048] fp32

  char* ws = (char*)d_ws;  // needs ~192 MiB
  bf16* xb     = (bf16*)(ws);                  // 33554432 B  x bf16
  bf16* wqkvT  = (bf16*)(ws + 33554432);       // 25165824 B  Wqkv^T
  bf16* wprojT = (bf16*)(ws + 58720256);       //  8388608 B  Wproj^T
  bf16* qb     = (bf16*)(ws + 67108864);       // 33554432 B  Q [BH][T][D]
  bf16* kb     = (bf16*)(ws + 100663296);      // 33554432 B  K [BH][T][D]
  bf16* vtb    = (bf16*)(ws + 134217728);      // 33554432 B  V^T [BH][D][T]
  bf16* ab     = (bf16*)(ws + 167772160);      // 33554432 B  attn out bf16

  cast_f32_bf16<<<8192, 256, 0, stream>>>(x, xb, 2097152);
  transpose_cast<<<dim3(192, 64), 256, 0, stream>>>(Wqkv, wqkvT, 2048, 6144);
  transpose_cast<<<dim3(64, 64), 256, 0, stream>>>(Wproj, wprojT, 2048, 2048);
  gemm256<0><<<768, 512, 0, stream>>>(xb, wqkvT, bqkv, 8192, 6144, 2048,
                                      nullptr, qb, kb, vtb);
  attn_kernel<<<dim3(16, 64), 256, 0, stream>>>(qb, kb, vtb, ab);
  gemm256<1><<<256, 512, 0, stream>>>(ab, wprojT, bproj, 8192, 2048, 2048,
                                      out, nullptr, nullptr, nullptr);
}

// Round 5
// 677.352 us; speedup vs baseline: 1.0968x; 1.0968x over previous
//
#include <hip/hip_runtime.h>

// ---------------------------------------------------------------------------
// Fused MHA: qkv = x@Wqkv+b ; causal attention ; out = attn@Wproj+b
// B=4, T=2048, C=2048, H=16, D=128. fp32 in/out, bf16 MFMA internally.
// ---------------------------------------------------------------------------

typedef __bf16 bf16;
typedef __bf16 bf16x8 __attribute__((ext_vector_type(8)));
typedef __bf16 bf16x4 __attribute__((ext_vector_type(4)));
typedef float f32x4 __attribute__((ext_vector_type(4)));

__device__ __forceinline__ void gload_lds16(const void* g, void* l) {
  __builtin_amdgcn_global_load_lds(
      (const __attribute__((address_space(1))) void*)g,
      (__attribute__((address_space(3))) void*)l, 16, 0, 0);
}

// ---------------------------------------------------------------------------
// cast fp32 -> bf16, 8 elems/thread
__global__ __launch_bounds__(256) void cast_f32_bf16(
    const float* __restrict__ in, bf16* __restrict__ out, int n8) {
  int i = blockIdx.x * 256 + threadIdx.x;
  if (i >= n8) return;
  const float4* p = (const float4*)in + (size_t)i * 2;
  float4 a = p[0], b = p[1];
  bf16x8 o8 = {(bf16)a.x, (bf16)a.y, (bf16)a.z, (bf16)a.w,
               (bf16)b.x, (bf16)b.y, (bf16)b.z, (bf16)b.w};
  *(bf16x8*)(out + (size_t)i * 8) = o8;
}

// ---------------------------------------------------------------------------
// W [R][C] fp32  ->  WT [C][R] bf16   (32x32 LDS tile transpose)
__global__ __launch_bounds__(256) void transpose_cast(
    const float* __restrict__ in, bf16* __restrict__ out, int R, int C) {
  __shared__ bf16 tile[32][33];
  const int r0 = blockIdx.y * 32, c0 = blockIdx.x * 32;
  const int tid = threadIdx.x;
  const int c = tid & 31, r = tid >> 5;
#pragma unroll
  for (int rr = r; rr < 32; rr += 8)
    tile[rr][c] = (bf16)in[(size_t)(r0 + rr) * C + c0 + c];
  __syncthreads();
  const int oc = tid >> 3;           // out row within tile (0..31)
  const int ok = (tid & 7) * 4;      // out col chunk
  bf16x4 v;
#pragma unroll
  for (int j = 0; j < 4; ++j) v[j] = tile[ok + j][oc];
  *(bf16x4*)&out[(size_t)(c0 + oc) * R + r0 + ok] = v;
}

// ---------------------------------------------------------------------------
// 256x256 GEMM, 2 half-K phases per K-tile: C = A @ BT^T + bias.
// A [M][K] bf16 row-major, BT [N][K] bf16. 512 thr = 8 waves (2M x 4N),
// BK=64 as 2 K-halves of 32. LDS 128 KiB: [2 dbuf][2 kh][256 rows][32 elem]
// per operand, 64B rows, swizzle byte-bit5 ^= row-bit3 applied both-sides
// (pre-XOR'd global source + XOR'd ds_read, rule #21).
// Schedule (per K-tile t, buf cur=t&1): phase kh in {0,1}:
//   issue 4 stage-loads (t+1, kh) into cur^1 -> 12 ds_read + 32 MFMA with
//   COMPILER-scheduled fine-grained lgkmcnt (m97 finding: near-optimal; no
//   hard lgkm walls, no sched_barrier) -> s_waitcnt vmcnt(4) (counted, never
//   0 in steady state; drains the half-tile the NEXT phase reads, issued a
//   full tile earlier) -> s_barrier. Only what the compiler can't do is
//   hand-written: cross-barrier counted vmcnt + buffer-reuse barriers.
// EPI 0: scatter Q [BH][T][D], K [BH][T][D], V^T [BH][D][T]; EPI 1: fp32+bias.
template <int EPI>
__global__ __launch_bounds__(512, 2) void gemm256(
    const bf16* __restrict__ A, const bf16* __restrict__ BT,
    const float* __restrict__ bias, int M, int N, int K,
    float* __restrict__ outf, bf16* __restrict__ qb, bf16* __restrict__ kb,
    bf16* __restrict__ vtb) {
  __shared__ bf16 As[2][2][256 * 32];  // 64 KB
  __shared__ bf16 Bs[2][2][256 * 32];  // 64 KB
  const int tid = threadIdx.x;
  const int lane = tid & 63, w = tid >> 6;
  const int wm = w >> 2, wn = w & 3;
  const int lr = lane & 15, lg = lane >> 4;

  // bijective XCD swizzle (gridDim.x % 8 == 0 for both instantiations)
  const int nwg = gridDim.x, cpx = nwg >> 3;
  const int swz = (blockIdx.x & 7) * cpx + (blockIdx.x >> 3);
  const int ntx = N >> 8;  // tiles along N
  const int m0 = (swz / ntx) * 256, n0 = (swz % ntx) * 256;

  // stage one 16KB half-tile (kh, operand) of K-tile kt into dbuf d.
  // dest linear; source col pre-XOR'd by row-bit3 (both-sides swizzle).
  auto STAGE_H = [&](int d, int skh, int sisB, int kt) {
    const bf16* src = sisB ? BT : A;
    const int r0 = sisB ? n0 : m0;
    bf16* lb = sisB ? &Bs[d][skh][0] : &As[d][skh][0];
#pragma unroll
    for (int c = 0; c < 2; ++c) {
      const int chunk = w * 2 + c;                    // 0..15 (1KB chunks)
      const int row = chunk * 16 + (lane >> 2);       // 0..255
      const int col = ((lane & 3) * 8) ^ (((row >> 3) & 1) << 4);
      gload_lds16(src + (size_t)(r0 + row) * K + kt * 64 + skh * 32 + col,
                  (char*)lb + chunk * 1024);
    }
  };
  // fragment reads (swizzled): logical (row, lg*8..+7) of K-half kh
  auto LDA = [&](int d, int kh, int mi) -> bf16x8 {
    const int row = wm * 128 + mi * 16 + lr;
    return *(const bf16x8*)((const char*)&As[d][kh][0] +
                            ((row * 64 + lg * 16) ^ ((lr >> 3) << 5)));
  };
  auto LDB = [&](int d, int kh, int ni) -> bf16x8 {
    const int row = wn * 64 + ni * 16 + lr;
    return *(const bf16x8*)((const char*)&Bs[d][kh][0] +
                            ((row * 64 + lg * 16) ^ ((lr >> 3) << 5)));
  };

  f32x4 acc[8][4] = {};
  const int NT = K >> 6;

  // one half-K compute: 12 ds_read + 32 MFMA, compiler-scheduled
  auto COMPUTE = [&](int d, int kh) {
    bf16x8 af[8], bfr[4];
#pragma unroll
    for (int mi = 0; mi < 8; ++mi) af[mi] = LDA(d, kh, mi);
#pragma unroll
    for (int ni = 0; ni < 4; ++ni) bfr[ni] = LDB(d, kh, ni);
#pragma unroll
    for (int mi = 0; mi < 8; ++mi)
#pragma unroll
      for (int ni = 0; ni < 4; ++ni)
        acc[mi][ni] = __builtin_amdgcn_mfma_f32_16x16x32_bf16(
            af[mi], bfr[ni], acc[mi][ni], 0, 0, 0);
  };

  // prologue: stage tile 0 fully; drain its kh0 (kh1 stays in flight)
  STAGE_H(0, 0, 0, 0);
  STAGE_H(0, 0, 1, 0);
  STAGE_H(0, 1, 0, 0);
  STAGE_H(0, 1, 1, 0);
  asm volatile("s_waitcnt vmcnt(4)" ::: "memory");
  __builtin_amdgcn_s_barrier();

  for (int t = 0; t < NT; ++t) {
    const int cur = t & 1;
    const bool pf = (t + 1 < NT);
    // ---- phase kh=0 ----
    if (pf) {
      STAGE_H(cur ^ 1, 0, 0, t + 1);
      STAGE_H(cur ^ 1, 0, 1, t + 1);
    }
    __builtin_amdgcn_s_setprio(1);
    COMPUTE(cur, 0);
    __builtin_amdgcn_s_setprio(0);
    if (pf) asm volatile("s_waitcnt vmcnt(4)" ::: "memory");
    else    asm volatile("s_waitcnt vmcnt(0)" ::: "memory");
    __builtin_amdgcn_s_barrier();  // kh1 of t now visible to all waves
    // ---- phase kh=1 ----
    if (pf) {
      STAGE_H(cur ^ 1, 1, 0, t + 1);
      STAGE_H(cur ^ 1, 1, 1, t + 1);
    }
    __builtin_amdgcn_s_setprio(1);
    COMPUTE(cur, 1);
    __builtin_amdgcn_s_setprio(0);
    if (pf) {
      asm volatile("s_waitcnt vmcnt(4)" ::: "memory");
      __builtin_amdgcn_s_barrier();  // kh0 of t+1 visible; buf cur free
    }
  }

  // epilogue: C/D layout col=lane&15, row=(lane>>4)*4+r  [m89/m91]
#pragma unroll
  for (int mi = 0; mi < 8; ++mi) {
    const int mbase = m0 + wm * 128 + mi * 16 + lg * 4;
#pragma unroll
    for (int ni = 0; ni < 4; ++ni) {
      const int n = n0 + wn * 64 + ni * 16 + lr;
      const float bv = bias[n];
      if (EPI == 1) {
#pragma unroll
        for (int r = 0; r < 4; ++r)
          outf[(size_t)(mbase + r) * N + n] = acc[mi][ni][r] + bv;
      } else {
        const int which = n >> 11;           // 0=q 1=k 2=v
        const int cc = n & 2047, h = cc >> 7, dd = cc & 127;
        const int b = mbase >> 11, t0 = mbase & 2047;  // 4-row group never
        const int bh = b * 16 + h;                     // crosses b boundary
        if (which == 2) {
          bf16x4 pk;
#pragma unroll
          for (int r = 0; r < 4; ++r) pk[r] = (bf16)(acc[mi][ni][r] + bv);
          *(bf16x4*)&vtb[((size_t)bh * 128 + dd) * 2048 + t0] = pk;
        } else {
          bf16* dst = (which == 0) ? qb : kb;
#pragma unroll
          for (int r = 0; r < 4; ++r)
            dst[((size_t)bh * 2048 + t0 + r) * 128 + dd] =
                (bf16)(acc[mi][ni][r] + bv);
        }
      }
    }
  }
}

// ---------------------------------------------------------------------------
// Flash attention, causal. grid = (T/128, B*H). 4 waves; each wave owns two
// 16-row q-groups sharing each staged K/V tile. (unchanged from round 2/3)
__global__ __launch_bounds__(256) void attn_kernel(
    const bf16* __restrict__ qb, const bf16* __restrict__ kb,
    const bf16* __restrict__ vtb, bf16* __restrict__ ob) {
  __shared__ bf16 Ks[2][64 * 128];  // 2 x 16 KB, swizzled
  __shared__ bf16 Vs[2][128 * 64];  // 2 x 16 KB, swizzled
  __shared__ bf16 Ps[4][16][72];    // per-wave P, pad 64->72
  const int tid = threadIdx.x, lane = tid & 63, w = tid >> 6;
  const int qt = (gridDim.x - 1) - blockIdx.x;  // big causal blocks first
  const int bh = blockIdx.y;
  const int lr = lane & 15, lg = lane >> 4;
  const int q0 = qt * 128;
  const size_t base = (size_t)bh * (2048 * 128);
  const int rswz = (lr & 7) << 3;  // read-side XOR (element domain)

  // hoist Q frags; fold (1/sqrt(D))*log2(e) so softmax runs in exp2 domain
  const float qscale = 0.08838834764831845f * 1.4426950408889634f;
  bf16x8 qf[2][4];
#pragma unroll
  for (int g = 0; g < 2; ++g) {
    const bf16* qp =
        qb + base + (size_t)(q0 + g * 64 + w * 16 + lr) * 128 + lg * 8;
#pragma unroll
    for (int kk = 0; kk < 4; ++kk) {
      bf16x8 t = *(const bf16x8*)(qp + kk * 32);
#pragma unroll
      for (int e = 0; e < 8; ++e) t[e] = (bf16)((float)t[e] * qscale);
      qf[g][kk] = t;
    }
  }

  f32x4 o[2][8] = {};
  float mst[2][4], lst[2][4];
#pragma unroll
  for (int g = 0; g < 2; ++g)
#pragma unroll
    for (int r = 0; r < 4; ++r) { mst[g][r] = -1e30f; lst[g][r] = 0.f; }

  // stage tile kt into buffer bsel (8 gload_lds / wave)
  auto STAGE = [&](int bsel, int kt) {
#pragma unroll
    for (int c = 0; c < 4; ++c) {
      const int L = w * 1024 + c * 4096 + lane * 16;  // lds byte offset
      {  // K tile rows 256B; pre-XOR source col so swizzled-read is logical
        const int row = L >> 8, ce = (L & 255) >> 1;
        gload_lds16(kb + base + (size_t)(kt * 64 + row) * 128 +
                        (ce ^ ((row & 7) << 3)),
                    (char*)Ks[bsel] + w * 1024 + c * 4096);
      }
      {  // V^T tile rows 128B
        const int d = L >> 7, ce = (L & 127) >> 1;
        gload_lds16(vtb + base + (size_t)d * 2048 + kt * 64 +
                        (ce ^ ((d & 7) << 3)),
                    (char*)Vs[bsel] + w * 1024 + c * 4096);
      }
    }
  };

  const int ntiles = 2 * qt + 2;
  STAGE(0, 0);
  for (int kt = 0; kt < ntiles; ++kt) {
    const int cur = kt & 1;
    if (kt + 1 < ntiles) {
      STAGE(cur ^ 1, kt + 1);
      asm volatile("s_waitcnt vmcnt(8)" ::: "memory");  // cur tile done,
    } else {                                            // next stays in flight
      asm volatile("s_waitcnt vmcnt(0)" ::: "memory");
    }
    __builtin_amdgcn_s_barrier();
    __builtin_amdgcn_sched_barrier(0);

    const bf16* Kc = Ks[cur];
    const bf16* Vc = Vs[cur];
#pragma unroll
    for (int g = 0; g < 2; ++g) {
      if (kt > 2 * qt + g) continue;  // uniform branch
      const bool diag = (kt == 2 * qt + g);

      // S = Q K^T : B-frag col=lr -> K row j*16+lr (swizzled read)
      f32x4 s[4] = {};
      __builtin_amdgcn_s_setprio(1);
#pragma unroll
      for (int kk = 0; kk < 4; ++kk)
#pragma unroll
        for (int j = 0; j < 4; ++j) {
          const bf16x8 kf = *(const bf16x8*)&Kc[(j * 16 + lr) * 128 +
                                               ((kk * 32 + lg * 8) ^ rswz)];
          s[j] = __builtin_amdgcn_mfma_f32_16x16x32_bf16(qf[g][kk], kf, s[j],
                                                         0, 0, 0);
        }
      __builtin_amdgcn_s_setprio(0);

      if (diag) {
#pragma unroll
        for (int j = 0; j < 4; ++j)
#pragma unroll
          for (int r = 0; r < 4; ++r) {
            const int qq = w * 16 + lg * 4 + r;
            if (j * 16 + lr > qq) s[j][r] = -1e30f;
          }
      }

      // online softmax (exp2 domain); q-row = 16 lanes of one lg-group
      float pmax[4];
#pragma unroll
      for (int r = 0; r < 4; ++r) {
        float pm = fmaxf(fmaxf(s[0][r], s[1][r]), fmaxf(s[2][r], s[3][r]));
        pm = fmaxf(pm, __shfl_xor(pm, 1, 16));
        pm = fmaxf(pm, __shfl_xor(pm, 2, 16));
        pm = fmaxf(pm, __shfl_xor(pm, 4, 16));
        pm = fmaxf(pm, __shfl_xor(pm, 8, 16));
        pmax[r] = pm;
      }
      bool need = false;
#pragma unroll
      for (int r = 0; r < 4; ++r) need |= (pmax[r] > mst[g][r]);
      if (__any(need)) {  // skip rescale pass when no row's max grew (exact)
#pragma unroll
        for (int r = 0; r < 4; ++r) {
          const float mnew = fmaxf(mst[g][r], pmax[r]);
          const float alpha = __builtin_amdgcn_exp2f(mst[g][r] - mnew);
          mst[g][r] = mnew;
          lst[g][r] *= alpha;
#pragma unroll
          for (int n = 0; n < 8; ++n) o[g][n][r] *= alpha;
        }
      }
      float rsum[4] = {0.f, 0.f, 0.f, 0.f};
#pragma unroll
      for (int j = 0; j < 4; ++j)
#pragma unroll
        for (int r = 0; r < 4; ++r) {
          const float p = __builtin_amdgcn_exp2f(s[j][r] - mst[g][r]);
          rsum[r] += p;
          Ps[w][lg * 4 + r][j * 16 + lr] = (bf16)p;
        }
#pragma unroll
      for (int r = 0; r < 4; ++r) {
        rsum[r] += __shfl_xor(rsum[r], 1, 16);
        rsum[r] += __shfl_xor(rsum[r], 2, 16);
        rsum[r] += __shfl_xor(rsum[r], 4, 16);
        rsum[r] += __shfl_xor(rsum[r], 8, 16);
        lst[g][r] += rsum[r];
      }

      // P (via per-wave LDS, within-wave ordering) @ V (swizzled read)
      bf16x8 pf[2];
#pragma unroll
      for (int kk = 0; kk < 2; ++kk)
        pf[kk] = *(const bf16x8*)&Ps[w][lr][kk * 32 + lg * 8];
      __builtin_amdgcn_s_setprio(1);
#pragma unroll
      for (int n = 0; n < 8; ++n)
#pragma unroll
        for (int kk = 0; kk < 2; ++kk) {
          const bf16x8 vf = *(const bf16x8*)&Vc[(n * 16 + lr) * 64 +
                                               ((kk * 32 + lg * 8) ^ rswz)];
          o[g][n] = __builtin_amdgcn_mfma_f32_16x16x32_bf16(pf[kk], vf,
                                                            o[g][n], 0, 0, 0);
        }
      __builtin_amdgcn_s_setprio(0);
    }
    __builtin_amdgcn_sched_barrier(0);
    __builtin_amdgcn_s_barrier();  // all reads of buf cur done before next
    __builtin_amdgcn_sched_barrier(0);  // STAGE overwrites it
  }

  // write attn-out as bf16 [B*T][C]
  const int b = bh >> 4, h = bh & 15;
#pragma unroll
  for (int g = 0; g < 2; ++g)
#pragma unroll
    for (int r = 0; r < 4; ++r) {
      const float inv = 1.0f / lst[g][r];
      const int t = q0 + g * 64 + w * 16 + lg * 4 + r;
      bf16* dst = ob + ((size_t)(b * 2048 + t)) * 2048 + h * 128;
#pragma unroll
      for (int n = 0; n < 8; ++n) dst[n * 16 + lr] = (bf16)(o[g][n][r] * inv);
    }
}

// ---------------------------------------------------------------------------
extern "C" void kernel_launch(void* const* d_in, const int* in_sizes, int n_in,
                              void* d_out, int out_size, void* d_ws,
                              size_t ws_size, hipStream_t stream) {
  const float* x = (const float*)d_in[0];      // [4,2048,2048]
  const float* Wqkv = (const float*)d_in[1];   // [2048,6144]
  const float* bqkv = (const float*)d_in[2];   // [6144]
  const float* Wproj = (const float*)d_in[3];  // [2048,2048]
  const float* bproj = (const float*)d_in[4];  // [2048]
  float* out = (float*)d_out;                  // [8192,2048] fp32

  char* ws = (char*)d_ws;  // needs ~192 MiB
  bf16* xb     = (bf16*)(ws);                  // 33554432 B  x bf16
  bf16* wqkvT  = (bf16*)(ws + 33554432);       // 25165824 B  Wqkv^T
  bf16* wprojT = (bf16*)(ws + 58720256);       //  8388608 B  Wproj^T
  bf16* qb     = (bf16*)(ws + 67108864);       // 33554432 B  Q [BH][T][D]
  bf16* kb     = (bf16*)(ws + 100663296);      // 33554432 B  K [BH][T][D]
  bf16* vtb    = (bf16*)(ws + 134217728);      // 33554432 B  V^T [BH][D][T]
  bf16* ab     = (bf16*)(ws + 167772160);      // 33554432 B  attn out bf16

  cast_f32_bf16<<<8192, 256, 0, stream>>>(x, xb, 2097152);
  transpose_cast<<<dim3(192, 64), 256, 0, stream>>>(Wqkv, wqkvT, 2048, 6144);
  transpose_cast<<<dim3(64, 64), 256, 0, stream>>>(Wproj, wprojT, 2048, 2048);
  gemm256<0><<<768, 512, 0, stream>>>(xb, wqkvT, bqkv, 8192, 6144, 2048,
                                      nullptr, qb, kb, vtb);
  attn_kernel<<<dim3(16, 64), 256, 0, stream>>>(qb, kb, vtb, ab);
  gemm256<1><<<256, 512, 0, stream>>>(ab, wprojT, bproj, 8192, 2048, 2048,
                                      out, nullptr, nullptr, nullptr);
}

// Round 7
// 613.172 us; speedup vs baseline: 1.2116x; 1.1047x over previous
//
#include <hip/hip_runtime.h>

// ---------------------------------------------------------------------------
// Fused MHA: qkv = x@Wqkv+b ; causal attention ; out = attn@Wproj+b
// B=4, T=2048, C=2048, H=16, D=128. fp32 in/out, bf16 MFMA internally.
// (Round 6 resubmit — container died on infra, not kernel; code unchanged.)
// ---------------------------------------------------------------------------

typedef __bf16 bf16;
typedef __bf16 bf16x8 __attribute__((ext_vector_type(8)));
typedef __bf16 bf16x4 __attribute__((ext_vector_type(4)));
typedef float f32x4 __attribute__((ext_vector_type(4)));

__device__ __forceinline__ void gload_lds16(const void* g, void* l) {
  __builtin_amdgcn_global_load_lds(
      (const __attribute__((address_space(1))) void*)g,
      (__attribute__((address_space(3))) void*)l, 16, 0, 0);
}

// ---------------------------------------------------------------------------
// cast fp32 -> bf16, 8 elems/thread
__global__ __launch_bounds__(256) void cast_f32_bf16(
    const float* __restrict__ in, bf16* __restrict__ out, int n8) {
  int i = blockIdx.x * 256 + threadIdx.x;
  if (i >= n8) return;
  const float4* p = (const float4*)in + (size_t)i * 2;
  float4 a = p[0], b = p[1];
  bf16x8 o8 = {(bf16)a.x, (bf16)a.y, (bf16)a.z, (bf16)a.w,
               (bf16)b.x, (bf16)b.y, (bf16)b.z, (bf16)b.w};
  *(bf16x8*)(out + (size_t)i * 8) = o8;
}

// ---------------------------------------------------------------------------
// W [R][C] fp32  ->  WT [C][R] bf16   (32x32 LDS tile transpose)
__global__ __launch_bounds__(256) void transpose_cast(
    const float* __restrict__ in, bf16* __restrict__ out, int R, int C) {
  __shared__ bf16 tile[32][33];
  const int r0 = blockIdx.y * 32, c0 = blockIdx.x * 32;
  const int tid = threadIdx.x;
  const int c = tid & 31, r = tid >> 5;
#pragma unroll
  for (int rr = r; rr < 32; rr += 8)
    tile[rr][c] = (bf16)in[(size_t)(r0 + rr) * C + c0 + c];
  __syncthreads();
  const int oc = tid >> 3;           // out row within tile (0..31)
  const int ok = (tid & 7) * 4;      // out col chunk
  bf16x4 v;
#pragma unroll
  for (int j = 0; j < 4; ++j) v[j] = tile[ok + j][oc];
  *(bf16x4*)&out[(size_t)(c0 + oc) * R + r0 + ok] = v;
}

// ---------------------------------------------------------------------------
// 256x256 GEMM, 2 half-K phases per K-tile (unchanged from round 5).
template <int EPI>
__global__ __launch_bounds__(512, 2) void gemm256(
    const bf16* __restrict__ A, const bf16* __restrict__ BT,
    const float* __restrict__ bias, int M, int N, int K,
    float* __restrict__ outf, bf16* __restrict__ qb, bf16* __restrict__ kb,
    bf16* __restrict__ vtb) {
  __shared__ bf16 As[2][2][256 * 32];  // 64 KB
  __shared__ bf16 Bs[2][2][256 * 32];  // 64 KB
  const int tid = threadIdx.x;
  const int lane = tid & 63, w = tid >> 6;
  const int wm = w >> 2, wn = w & 3;
  const int lr = lane & 15, lg = lane >> 4;

  // bijective XCD swizzle (gridDim.x % 8 == 0 for both instantiations)
  const int nwg = gridDim.x, cpx = nwg >> 3;
  const int swz = (blockIdx.x & 7) * cpx + (blockIdx.x >> 3);
  const int ntx = N >> 8;  // tiles along N
  const int m0 = (swz / ntx) * 256, n0 = (swz % ntx) * 256;

  // stage one 16KB half-tile (kh, operand) of K-tile kt into dbuf d.
  // dest linear; source col pre-XOR'd by row-bit3 (both-sides swizzle).
  auto STAGE_H = [&](int d, int skh, int sisB, int kt) {
    const bf16* src = sisB ? BT : A;
    const int r0 = sisB ? n0 : m0;
    bf16* lb = sisB ? &Bs[d][skh][0] : &As[d][skh][0];
#pragma unroll
    for (int c = 0; c < 2; ++c) {
      const int chunk = w * 2 + c;                    // 0..15 (1KB chunks)
      const int row = chunk * 16 + (lane >> 2);       // 0..255
      const int col = ((lane & 3) * 8) ^ (((row >> 3) & 1) << 4);
      gload_lds16(src + (size_t)(r0 + row) * K + kt * 64 + skh * 32 + col,
                  (char*)lb + chunk * 1024);
    }
  };
  // fragment reads (swizzled): logical (row, lg*8..+7) of K-half kh
  auto LDA = [&](int d, int kh, int mi) -> bf16x8 {
    const int row = wm * 128 + mi * 16 + lr;
    return *(const bf16x8*)((const char*)&As[d][kh][0] +
                            ((row * 64 + lg * 16) ^ ((lr >> 3) << 5)));
  };
  auto LDB = [&](int d, int kh, int ni) -> bf16x8 {
    const int row = wn * 64 + ni * 16 + lr;
    return *(const bf16x8*)((const char*)&Bs[d][kh][0] +
                            ((row * 64 + lg * 16) ^ ((lr >> 3) << 5)));
  };

  f32x4 acc[8][4] = {};
  const int NT = K >> 6;

  // one half-K compute: 12 ds_read + 32 MFMA, compiler-scheduled
  auto COMPUTE = [&](int d, int kh) {
    bf16x8 af[8], bfr[4];
#pragma unroll
    for (int mi = 0; mi < 8; ++mi) af[mi] = LDA(d, kh, mi);
#pragma unroll
    for (int ni = 0; ni < 4; ++ni) bfr[ni] = LDB(d, kh, ni);
#pragma unroll
    for (int mi = 0; mi < 8; ++mi)
#pragma unroll
      for (int ni = 0; ni < 4; ++ni)
        acc[mi][ni] = __builtin_amdgcn_mfma_f32_16x16x32_bf16(
            af[mi], bfr[ni], acc[mi][ni], 0, 0, 0);
  };

  // prologue: stage tile 0 fully; drain its kh0 (kh1 stays in flight)
  STAGE_H(0, 0, 0, 0);
  STAGE_H(0, 0, 1, 0);
  STAGE_H(0, 1, 0, 0);
  STAGE_H(0, 1, 1, 0);
  asm volatile("s_waitcnt vmcnt(4)" ::: "memory");
  __builtin_amdgcn_s_barrier();

  for (int t = 0; t < NT; ++t) {
    const int cur = t & 1;
    const bool pf = (t + 1 < NT);
    // ---- phase kh=0 ----
    if (pf) {
      STAGE_H(cur ^ 1, 0, 0, t + 1);
      STAGE_H(cur ^ 1, 0, 1, t + 1);
    }
    __builtin_amdgcn_s_setprio(1);
    COMPUTE(cur, 0);
    __builtin_amdgcn_s_setprio(0);
    if (pf) asm volatile("s_waitcnt vmcnt(4)" ::: "memory");
    else    asm volatile("s_waitcnt vmcnt(0)" ::: "memory");
    __builtin_amdgcn_s_barrier();  // kh1 of t now visible to all waves
    // ---- phase kh=1 ----
    if (pf) {
      STAGE_H(cur ^ 1, 1, 0, t + 1);
      STAGE_H(cur ^ 1, 1, 1, t + 1);
    }
    __builtin_amdgcn_s_setprio(1);
    COMPUTE(cur, 1);
    __builtin_amdgcn_s_setprio(0);
    if (pf) {
      asm volatile("s_waitcnt vmcnt(4)" ::: "memory");
      __builtin_amdgcn_s_barrier();  // kh0 of t+1 visible; buf cur free
    }
  }

  // epilogue: C/D layout col=lane&15, row=(lane>>4)*4+r  [m89/m91]
#pragma unroll
  for (int mi = 0; mi < 8; ++mi) {
    const int mbase = m0 + wm * 128 + mi * 16 + lg * 4;
#pragma unroll
    for (int ni = 0; ni < 4; ++ni) {
      const int n = n0 + wn * 64 + ni * 16 + lr;
      const float bv = bias[n];
      if (EPI == 1) {
#pragma unroll
        for (int r = 0; r < 4; ++r)
          outf[(size_t)(mbase + r) * N + n] = acc[mi][ni][r] + bv;
      } else {
        const int which = n >> 11;           // 0=q 1=k 2=v
        const int cc = n & 2047, h = cc >> 7, dd = cc & 127;
        const int b = mbase >> 11, t0 = mbase & 2047;  // 4-row group never
        const int bh = b * 16 + h;                     // crosses b boundary
        if (which == 2) {
          bf16x4 pk;
#pragma unroll
          for (int r = 0; r < 4; ++r) pk[r] = (bf16)(acc[mi][ni][r] + bv);
          *(bf16x4*)&vtb[((size_t)bh * 128 + dd) * 2048 + t0] = pk;
        } else {
          bf16* dst = (which == 0) ? qb : kb;
#pragma unroll
          for (int r = 0; r < 4; ++r)
            dst[((size_t)bh * 2048 + t0 + r) * 128 + dd] =
                (bf16)(acc[mi][ni][r] + bv);
        }
      }
    }
  }
}

// ---------------------------------------------------------------------------
// Flash attention, causal, WORK-BALANCED pairing. grid = (8, B*H), 512 thr.
// Block x owns q-tiles qtA = x (waves 0-3) and qtB = 15-x (waves 4-7):
// every block does exactly 34 group-steps of compute. All 8 waves co-stage
// the shared K/V tiles (B's kt range contains A's). Per wave: 2 q-groups of
// 16 rows. K/V LDS dbuf + counted vmcnt + XOR swizzle as before.
__global__ __launch_bounds__(512) void attn_kernel(
    const bf16* __restrict__ qb, const bf16* __restrict__ kb,
    const bf16* __restrict__ vtb, bf16* __restrict__ ob) {
  __shared__ bf16 Ks[2][64 * 128];  // 2 x 16 KB, swizzled
  __shared__ bf16 Vs[2][128 * 64];  // 2 x 16 KB, swizzled
  __shared__ bf16 Ps[8][16][72];    // per-wave P, pad 64->72 (18 KB)
  const int tid = threadIdx.x, lane = tid & 63, w = tid >> 6;
  const int bh = blockIdx.y;
  const int qtA = blockIdx.x;            // 0..7
  const int qtB = 15 - qtA;              // 8..15
  const int qt_w = (w < 4) ? qtA : qtB;  // this wave's q-tile
  const int wq = w & 3;                  // wave slot within its q-tile
  const int lr = lane & 15, lg = lane >> 4;
  const int q0 = qt_w * 128;
  const size_t base = (size_t)bh * (2048 * 128);
  const int rswz = (lr & 7) << 3;  // read-side XOR (element domain)

  // hoist Q frags; fold (1/sqrt(D))*log2(e) so softmax runs in exp2 domain
  const float qscale = 0.08838834764831845f * 1.4426950408889634f;
  bf16x8 qf[2][4];
#pragma unroll
  for (int g = 0; g < 2; ++g) {
    const bf16* qp =
        qb + base + (size_t)(q0 + g * 64 + wq * 16 + lr) * 128 + lg * 8;
#pragma unroll
    for (int kk = 0; kk < 4; ++kk) {
      bf16x8 t = *(const bf16x8*)(qp + kk * 32);
#pragma unroll
      for (int e = 0; e < 8; ++e) t[e] = (bf16)((float)t[e] * qscale);
      qf[g][kk] = t;
    }
  }

  f32x4 o[2][8] = {};
  float mst[2][4], lst[2][4];
#pragma unroll
  for (int g = 0; g < 2; ++g)
#pragma unroll
    for (int r = 0; r < 4; ++r) { mst[g][r] = -1e30f; lst[g][r] = 0.f; }

  // stage tile kt into buffer bsel: 512 threads x 2 sweeps x (K+V) -> 4
  // gload_lds per thread. dest linear per wave; source col pre-XOR'd.
  auto STAGE = [&](int bsel, int kt) {
#pragma unroll
    for (int c = 0; c < 2; ++c) {
      const int L = w * 1024 + c * 8192 + lane * 16;  // byte offset in 16KB
      {  // K tile rows 256B
        const int row = L >> 8, ce = (L & 255) >> 1;
        gload_lds16(kb + base + (size_t)(kt * 64 + row) * 128 +
                        (ce ^ ((row & 7) << 3)),
                    (char*)Ks[bsel] + w * 1024 + c * 8192);
      }
      {  // V^T tile rows 128B
        const int d = L >> 7, ce = (L & 127) >> 1;
        gload_lds16(vtb + base + (size_t)d * 2048 + kt * 64 +
                        (ce ^ ((d & 7) << 3)),
                    (char*)Vs[bsel] + w * 1024 + c * 8192);
      }
    }
  };

  const int nst = 2 * qtB + 2;  // staged tiles (covers A's range too)
  STAGE(0, 0);                  // 4 outstanding; drained by iter 0's vmcnt(4)
  for (int kt = 0; kt < nst; ++kt) {
    const int cur = kt & 1;
    if (kt + 1 < nst) {
      STAGE(cur ^ 1, kt + 1);  // 4 more in flight
      asm volatile("s_waitcnt vmcnt(4)" ::: "memory");  // tile kt landed
    } else {
      asm volatile("s_waitcnt vmcnt(0)" ::: "memory");
    }
    __builtin_amdgcn_s_barrier();  // all waves' staging of kt visible
    __builtin_amdgcn_sched_barrier(0);

    const bf16* Kc = Ks[cur];
    const bf16* Vc = Vs[cur];
#pragma unroll
    for (int g = 0; g < 2; ++g) {
      if (kt > 2 * qt_w + g) continue;  // wave-uniform: past this group's diag
      const bool diag = (kt == 2 * qt_w + g);

      // S = Q K^T : B-frag col=lr -> K row j*16+lr (swizzled read)
      f32x4 s[4] = {};
      __builtin_amdgcn_s_setprio(1);
#pragma unroll
      for (int kk = 0; kk < 4; ++kk)
#pragma unroll
        for (int j = 0; j < 4; ++j) {
          const bf16x8 kf = *(const bf16x8*)&Kc[(j * 16 + lr) * 128 +
                                               ((kk * 32 + lg * 8) ^ rswz)];
          s[j] = __builtin_amdgcn_mfma_f32_16x16x32_bf16(qf[g][kk], kf, s[j],
                                                         0, 0, 0);
        }
      __builtin_amdgcn_s_setprio(0);

      if (diag) {
#pragma unroll
        for (int j = 0; j < 4; ++j)
#pragma unroll
          for (int r = 0; r < 4; ++r) {
            const int qq = wq * 16 + lg * 4 + r;  // q rel in 64-row group
            if (j * 16 + lr > qq) s[j][r] = -1e30f;
          }
      }

      // online softmax (exp2 domain); q-row = 16 lanes of one lg-group
      float pmax[4];
#pragma unroll
      for (int r = 0; r < 4; ++r) {
        float pm = fmaxf(fmaxf(s[0][r], s[1][r]), fmaxf(s[2][r], s[3][r]));
        pm = fmaxf(pm, __shfl_xor(pm, 1, 16));
        pm = fmaxf(pm, __shfl_xor(pm, 2, 16));
        pm = fmaxf(pm, __shfl_xor(pm, 4, 16));
        pm = fmaxf(pm, __shfl_xor(pm, 8, 16));
        pmax[r] = pm;
      }
      bool need = false;
#pragma unroll
      for (int r = 0; r < 4; ++r) need |= (pmax[r] > mst[g][r]);
      if (__any(need)) {  // skip rescale pass when no row's max grew (exact)
#pragma unroll
        for (int r = 0; r < 4; ++r) {
          const float mnew = fmaxf(mst[g][r], pmax[r]);
          const float alpha = __builtin_amdgcn_exp2f(mst[g][r] - mnew);
          mst[g][r] = mnew;
          lst[g][r] *= alpha;
#pragma unroll
          for (int n = 0; n < 8; ++n) o[g][n][r] *= alpha;
        }
      }
      float rsum[4] = {0.f, 0.f, 0.f, 0.f};
#pragma unroll
      for (int j = 0; j < 4; ++j)
#pragma unroll
        for (int r = 0; r < 4; ++r) {
          const float p = __builtin_amdgcn_exp2f(s[j][r] - mst[g][r]);
          rsum[r] += p;
          Ps[w][lg * 4 + r][j * 16 + lr] = (bf16)p;
        }
#pragma unroll
      for (int r = 0; r < 4; ++r) {
        rsum[r] += __shfl_xor(rsum[r], 1, 16);
        rsum[r] += __shfl_xor(rsum[r], 2, 16);
        rsum[r] += __shfl_xor(rsum[r], 4, 16);
        rsum[r] += __shfl_xor(rsum[r], 8, 16);
        lst[g][r] += rsum[r];
      }

      // P (via per-wave LDS, within-wave ordering) @ V (swizzled read)
      bf16x8 pf[2];
#pragma unroll
      for (int kk = 0; kk < 2; ++kk)
        pf[kk] = *(const bf16x8*)&Ps[w][lr][kk * 32 + lg * 8];
      __builtin_amdgcn_s_setprio(1);
#pragma unroll
      for (int n = 0; n < 8; ++n)
#pragma unroll
        for (int kk = 0; kk < 2; ++kk) {
          const bf16x8 vf = *(const bf16x8*)&Vc[(n * 16 + lr) * 64 +
                                               ((kk * 32 + lg * 8) ^ rswz)];
          o[g][n] = __builtin_amdgcn_mfma_f32_16x16x32_bf16(pf[kk], vf,
                                                            o[g][n], 0, 0, 0);
        }
      __builtin_amdgcn_s_setprio(0);
    }
    __builtin_amdgcn_sched_barrier(0);
    __builtin_amdgcn_s_barrier();  // all reads of buf cur done before next
    __builtin_amdgcn_sched_barrier(0);  // STAGE overwrites it
  }

  // write attn-out as bf16 [B*T][C]
  const int b = bh >> 4, h = bh & 15;
#pragma unroll
  for (int g = 0; g < 2; ++g)
#pragma unroll
    for (int r = 0; r < 4; ++r) {
      const float inv = 1.0f / lst[g][r];
      const int t = q0 + g * 64 + wq * 16 + lg * 4 + r;
      bf16* dst = ob + ((size_t)(b * 2048 + t)) * 2048 + h * 128;
#pragma unroll
      for (int n = 0; n < 8; ++n) dst[n * 16 + lr] = (bf16)(o[g][n][r] * inv);
    }
}

// ---------------------------------------------------------------------------
extern "C" void kernel_launch(void* const* d_in, const int* in_sizes, int n_in,
                              void* d_out, int out_size, void* d_ws,
                              size_t ws_size, hipStream_t stream) {
  const float* x = (const float*)d_in[0];      // [4,2048,2048]
  const float* Wqkv = (const float*)d_in[1];   // [2048,6144]
  const float* bqkv = (const float*)d_in[2];   // [6144]
  const float* Wproj = (const float*)d_in[3];  // [2048,2048]
  const float* bproj = (const float*)d_in[4];  // [2048]
  float* out = (float*)d_out;                  // [8192,2048] fp32

  char* ws = (char*)d_ws;  // needs ~192 MiB
  bf16* xb     = (bf16*)(ws);                  // 33554432 B  x bf16
  bf16* wqkvT  = (bf16*)(ws + 33554432);       // 25165824 B  Wqkv^T
  bf16* wprojT = (bf16*)(ws + 58720256);       //  8388608 B  Wproj^T
  bf16* qb     = (bf16*)(ws + 67108864);       // 33554432 B  Q [BH][T][D]
  bf16* kb     = (bf16*)(ws + 100663296);      // 33554432 B  K [BH][T][D]
  bf16* vtb    = (bf16*)(ws + 134217728);      // 33554432 B  V^T [BH][D][T]
  bf16* ab     = (bf16*)(ws + 167772160);      // 33554432 B  attn out bf16

  cast_f32_bf16<<<8192, 256, 0, stream>>>(x, xb, 2097152);
  transpose_cast<<<dim3(192, 64), 256, 0, stream>>>(Wqkv, wqkvT, 2048, 6144);
  transpose_cast<<<dim3(64, 64), 256, 0, stream>>>(Wproj, wprojT, 2048, 2048);
  gemm256<0><<<768, 512, 0, stream>>>(xb, wqkvT, bqkv, 8192, 6144, 2048,
                                      nullptr, qb, kb, vtb);
  attn_kernel<<<dim3(8, 64), 512, 0, stream>>>(qb, kb, vtb, ab);
  gemm256<1><<<256, 512, 0, stream>>>(ab, wprojT, bproj, 8192, 2048, 2048,
                                      out, nullptr, nullptr, nullptr);
}

// Round 8
// 606.311 us; speedup vs baseline: 1.2253x; 1.0113x over previous
//
#include <hip/hip_runtime.h>

// ---------------------------------------------------------------------------
// Fused MHA: qkv = x@Wqkv+b ; causal attention ; out = attn@Wproj+b
// B=4, T=2048, C=2048, H=16, D=128. fp32 in/out, bf16 MFMA internally.
// ---------------------------------------------------------------------------

typedef __bf16 bf16;
typedef __bf16 bf16x8 __attribute__((ext_vector_type(8)));
typedef __bf16 bf16x4 __attribute__((ext_vector_type(4)));
typedef float f32x4 __attribute__((ext_vector_type(4)));

__device__ __forceinline__ void gload_lds16(const void* g, void* l) {
  __builtin_amdgcn_global_load_lds(
      (const __attribute__((address_space(1))) void*)g,
      (__attribute__((address_space(3))) void*)l, 16, 0, 0);
}

// ---------------------------------------------------------------------------
// cast fp32 -> bf16, 8 elems/thread
__global__ __launch_bounds__(256) void cast_f32_bf16(
    const float* __restrict__ in, bf16* __restrict__ out, int n8) {
  int i = blockIdx.x * 256 + threadIdx.x;
  if (i >= n8) return;
  const float4* p = (const float4*)in + (size_t)i * 2;
  float4 a = p[0], b = p[1];
  bf16x8 o8 = {(bf16)a.x, (bf16)a.y, (bf16)a.z, (bf16)a.w,
               (bf16)b.x, (bf16)b.y, (bf16)b.z, (bf16)b.w};
  *(bf16x8*)(out + (size_t)i * 8) = o8;
}

// ---------------------------------------------------------------------------
// W [R][C] fp32  ->  WT [C][R] bf16   (32x32 LDS tile transpose)
__global__ __launch_bounds__(256) void transpose_cast(
    const float* __restrict__ in, bf16* __restrict__ out, int R, int C) {
  __shared__ bf16 tile[32][33];
  const int r0 = blockIdx.y * 32, c0 = blockIdx.x * 32;
  const int tid = threadIdx.x;
  const int c = tid & 31, r = tid >> 5;
#pragma unroll
  for (int rr = r; rr < 32; rr += 8)
    tile[rr][c] = (bf16)in[(size_t)(r0 + rr) * C + c0 + c];
  __syncthreads();
  const int oc = tid >> 3;           // out row within tile (0..31)
  const int ok = (tid & 7) * 4;      // out col chunk
  bf16x4 v;
#pragma unroll
  for (int j = 0; j < 4; ++j) v[j] = tile[ok + j][oc];
  *(bf16x4*)&out[(size_t)(c0 + oc) * R + r0 + ok] = v;
}

// ---------------------------------------------------------------------------
// 256x256 GEMM: C = A @ BT^T + bias. A [M][K] bf16 row-major, BT [N][K] bf16.
// 512 thr = 8 waves (2M x 4N), BK=64. LDS 128 KiB dbuf, 64B rows, swizzle
// byte-bit5 ^= row-bit3 applied both-sides (pre-XOR'd source + XOR'd read).
// Schedule per K-tile t (ONE barrier + ONE vmcnt per tile; mid-tile pair
// removed — kh1's data was staged a full tile earlier and is already
// visible from the tile-start barrier):
//   issue all 8 stage loads for t+1 -> setprio(1) -> COMPUTE kh0 + kh1
//   (24 ds_read + 64 MFMA in one compiler-scheduled scope) -> setprio(0)
//   -> vmcnt(0) (loads are ~5000cy old by now: near-free drain) -> barrier.
// EPI 0: scatter Q [BH][T][D], K [BH][T][D], V^T [BH][D][T]; EPI 1: fp32+bias.
template <int EPI>
__global__ __launch_bounds__(512, 2) void gemm256(
    const bf16* __restrict__ A, const bf16* __restrict__ BT,
    const float* __restrict__ bias, int M, int N, int K,
    float* __restrict__ outf, bf16* __restrict__ qb, bf16* __restrict__ kb,
    bf16* __restrict__ vtb) {
  __shared__ bf16 As[2][2][256 * 32];  // 64 KB
  __shared__ bf16 Bs[2][2][256 * 32];  // 64 KB
  const int tid = threadIdx.x;
  const int lane = tid & 63, w = tid >> 6;
  const int wm = w >> 2, wn = w & 3;
  const int lr = lane & 15, lg = lane >> 4;

  // bijective XCD swizzle (gridDim.x % 8 == 0 for both instantiations)
  const int nwg = gridDim.x, cpx = nwg >> 3;
  const int swz = (blockIdx.x & 7) * cpx + (blockIdx.x >> 3);
  const int ntx = N >> 8;  // tiles along N
  const int m0 = (swz / ntx) * 256, n0 = (swz % ntx) * 256;

  // stage one 16KB half-tile (kh, operand) of K-tile kt into dbuf d.
  // dest linear; source col pre-XOR'd by row-bit3 (both-sides swizzle).
  auto STAGE_H = [&](int d, int skh, int sisB, int kt) {
    const bf16* src = sisB ? BT : A;
    const int r0 = sisB ? n0 : m0;
    bf16* lb = sisB ? &Bs[d][skh][0] : &As[d][skh][0];
#pragma unroll
    for (int c = 0; c < 2; ++c) {
      const int chunk = w * 2 + c;                    // 0..15 (1KB chunks)
      const int row = chunk * 16 + (lane >> 2);       // 0..255
      const int col = ((lane & 3) * 8) ^ (((row >> 3) & 1) << 4);
      gload_lds16(src + (size_t)(r0 + row) * K + kt * 64 + skh * 32 + col,
                  (char*)lb + chunk * 1024);
    }
  };
  // fragment reads (swizzled): logical (row, lg*8..+7) of K-half kh
  auto LDA = [&](int d, int kh, int mi) -> bf16x8 {
    const int row = wm * 128 + mi * 16 + lr;
    return *(const bf16x8*)((const char*)&As[d][kh][0] +
                            ((row * 64 + lg * 16) ^ ((lr >> 3) << 5)));
  };
  auto LDB = [&](int d, int kh, int ni) -> bf16x8 {
    const int row = wn * 64 + ni * 16 + lr;
    return *(const bf16x8*)((const char*)&Bs[d][kh][0] +
                            ((row * 64 + lg * 16) ^ ((lr >> 3) << 5)));
  };

  f32x4 acc[8][4] = {};
  const int NT = K >> 6;

  // one half-K compute: 12 ds_read + 32 MFMA, compiler-scheduled
  auto COMPUTE = [&](int d, int kh) {
    bf16x8 af[8], bfr[4];
#pragma unroll
    for (int mi = 0; mi < 8; ++mi) af[mi] = LDA(d, kh, mi);
#pragma unroll
    for (int ni = 0; ni < 4; ++ni) bfr[ni] = LDB(d, kh, ni);
#pragma unroll
    for (int mi = 0; mi < 8; ++mi)
#pragma unroll
      for (int ni = 0; ni < 4; ++ni)
        acc[mi][ni] = __builtin_amdgcn_mfma_f32_16x16x32_bf16(
            af[mi], bfr[ni], acc[mi][ni], 0, 0, 0);
  };

  // prologue: stage tile 0 fully, drain, sync
  STAGE_H(0, 0, 0, 0);
  STAGE_H(0, 0, 1, 0);
  STAGE_H(0, 1, 0, 0);
  STAGE_H(0, 1, 1, 0);
  asm volatile("s_waitcnt vmcnt(0)" ::: "memory");
  __builtin_amdgcn_s_barrier();

  for (int t = 0; t < NT; ++t) {
    const int cur = t & 1;
    if (t + 1 < NT) {  // issue next tile's 8 loads; they fly under 64 MFMA
      STAGE_H(cur ^ 1, 0, 0, t + 1);
      STAGE_H(cur ^ 1, 0, 1, t + 1);
      STAGE_H(cur ^ 1, 1, 0, t + 1);
      STAGE_H(cur ^ 1, 1, 1, t + 1);
    }
    __builtin_amdgcn_s_setprio(1);
    COMPUTE(cur, 0);
    COMPUTE(cur, 1);
    __builtin_amdgcn_s_setprio(0);
    asm volatile("s_waitcnt vmcnt(0)" ::: "memory");  // ~5000cy-old loads
    __builtin_amdgcn_s_barrier();  // buf cur free + t+1 data visible
  }

  // epilogue: C/D layout col=lane&15, row=(lane>>4)*4+r  [m89/m91]
#pragma unroll
  for (int mi = 0; mi < 8; ++mi) {
    const int mbase = m0 + wm * 128 + mi * 16 + lg * 4;
#pragma unroll
    for (int ni = 0; ni < 4; ++ni) {
      const int n = n0 + wn * 64 + ni * 16 + lr;
      const float bv = bias[n];
      if (EPI == 1) {
#pragma unroll
        for (int r = 0; r < 4; ++r)
          outf[(size_t)(mbase + r) * N + n] = acc[mi][ni][r] + bv;
      } else {
        const int which = n >> 11;           // 0=q 1=k 2=v
        const int cc = n & 2047, h = cc >> 7, dd = cc & 127;
        const int b = mbase >> 11, t0 = mbase & 2047;  // 4-row group never
        const int bh = b * 16 + h;                     // crosses b boundary
        if (which == 2) {
          bf16x4 pk;
#pragma unroll
          for (int r = 0; r < 4; ++r) pk[r] = (bf16)(acc[mi][ni][r] + bv);
          *(bf16x4*)&vtb[((size_t)bh * 128 + dd) * 2048 + t0] = pk;
        } else {
          bf16* dst = (which == 0) ? qb : kb;
#pragma unroll
          for (int r = 0; r < 4; ++r)
            dst[((size_t)bh * 2048 + t0 + r) * 128 + dd] =
                (bf16)(acc[mi][ni][r] + bv);
        }
      }
    }
  }
}

// ---------------------------------------------------------------------------
// Flash attention, causal, WORK-BALANCED pairing. grid = (8, B*H), 512 thr.
// Block x owns q-tiles qtA = x (waves 0-3) and qtB = 15-x (waves 4-7):
// every block does exactly 34 group-steps of compute. All 8 waves co-stage
// the shared K/V tiles (B's kt range contains A's). Per wave: 2 q-groups of
// 16 rows. K/V LDS dbuf + counted vmcnt + XOR swizzle. (unchanged)
__global__ __launch_bounds__(512) void attn_kernel(
    const bf16* __restrict__ qb, const bf16* __restrict__ kb,
    const bf16* __restrict__ vtb, bf16* __restrict__ ob) {
  __shared__ bf16 Ks[2][64 * 128];  // 2 x 16 KB, swizzled
  __shared__ bf16 Vs[2][128 * 64];  // 2 x 16 KB, swizzled
  __shared__ bf16 Ps[8][16][72];    // per-wave P, pad 64->72 (18 KB)
  const int tid = threadIdx.x, lane = tid & 63, w = tid >> 6;
  const int bh = blockIdx.y;
  const int qtA = blockIdx.x;            // 0..7
  const int qtB = 15 - qtA;              // 8..15
  const int qt_w = (w < 4) ? qtA : qtB;  // this wave's q-tile
  const int wq = w & 3;                  // wave slot within its q-tile
  const int lr = lane & 15, lg = lane >> 4;
  const int q0 = qt_w * 128;
  const size_t base = (size_t)bh * (2048 * 128);
  const int rswz = (lr & 7) << 3;  // read-side XOR (element domain)

  // hoist Q frags; fold (1/sqrt(D))*log2(e) so softmax runs in exp2 domain
  const float qscale = 0.08838834764831845f * 1.4426950408889634f;
  bf16x8 qf[2][4];
#pragma unroll
  for (int g = 0; g < 2; ++g) {
    const bf16* qp =
        qb + base + (size_t)(q0 + g * 64 + wq * 16 + lr) * 128 + lg * 8;
#pragma unroll
    for (int kk = 0; kk < 4; ++kk) {
      bf16x8 t = *(const bf16x8*)(qp + kk * 32);
#pragma unroll
      for (int e = 0; e < 8; ++e) t[e] = (bf16)((float)t[e] * qscale);
      qf[g][kk] = t;
    }
  }

  f32x4 o[2][8] = {};
  float mst[2][4], lst[2][4];
#pragma unroll
  for (int g = 0; g < 2; ++g)
#pragma unroll
    for (int r = 0; r < 4; ++r) { mst[g][r] = -1e30f; lst[g][r] = 0.f; }

  // stage tile kt into buffer bsel: 512 threads x 2 sweeps x (K+V) -> 4
  // gload_lds per thread. dest linear per wave; source col pre-XOR'd.
  auto STAGE = [&](int bsel, int kt) {
#pragma unroll
    for (int c = 0; c < 2; ++c) {
      const int L = w * 1024 + c * 8192 + lane * 16;  // byte offset in 16KB
      {  // K tile rows 256B
        const int row = L >> 8, ce = (L & 255) >> 1;
        gload_lds16(kb + base + (size_t)(kt * 64 + row) * 128 +
                        (ce ^ ((row & 7) << 3)),
                    (char*)Ks[bsel] + w * 1024 + c * 8192);
      }
      {  // V^T tile rows 128B
        const int d = L >> 7, ce = (L & 127) >> 1;
        gload_lds16(vtb + base + (size_t)d * 2048 + kt * 64 +
                        (ce ^ ((d & 7) << 3)),
                    (char*)Vs[bsel] + w * 1024 + c * 8192);
      }
    }
  };

  const int nst = 2 * qtB + 2;  // staged tiles (covers A's range too)
  STAGE(0, 0);                  // 4 outstanding; drained by iter 0's vmcnt(4)
  for (int kt = 0; kt < nst; ++kt) {
    const int cur = kt & 1;
    if (kt + 1 < nst) {
      STAGE(cur ^ 1, kt + 1);  // 4 more in flight
      asm volatile("s_waitcnt vmcnt(4)" ::: "memory");  // tile kt landed
    } else {
      asm volatile("s_waitcnt vmcnt(0)" ::: "memory");
    }
    __builtin_amdgcn_s_barrier();  // all waves' staging of kt visible
    __builtin_amdgcn_sched_barrier(0);

    const bf16* Kc = Ks[cur];
    const bf16* Vc = Vs[cur];
#pragma unroll
    for (int g = 0; g < 2; ++g) {
      if (kt > 2 * qt_w + g) continue;  // wave-uniform: past this group's diag
      const bool diag = (kt == 2 * qt_w + g);

      // S = Q K^T : B-frag col=lr -> K row j*16+lr (swizzled read)
      f32x4 s[4] = {};
      __builtin_amdgcn_s_setprio(1);
#pragma unroll
      for (int kk = 0; kk < 4; ++kk)
#pragma unroll
        for (int j = 0; j < 4; ++j) {
          const bf16x8 kf = *(const bf16x8*)&Kc[(j * 16 + lr) * 128 +
                                               ((kk * 32 + lg * 8) ^ rswz)];
          s[j] = __builtin_amdgcn_mfma_f32_16x16x32_bf16(qf[g][kk], kf, s[j],
                                                         0, 0, 0);
        }
      __builtin_amdgcn_s_setprio(0);

      if (diag) {
#pragma unroll
        for (int j = 0; j < 4; ++j)
#pragma unroll
          for (int r = 0; r < 4; ++r) {
            const int qq = wq * 16 + lg * 4 + r;  // q rel in 64-row group
            if (j * 16 + lr > qq) s[j][r] = -1e30f;
          }
      }

      // online softmax (exp2 domain); q-row = 16 lanes of one lg-group
      float pmax[4];
#pragma unroll
      for (int r = 0; r < 4; ++r) {
        float pm = fmaxf(fmaxf(s[0][r], s[1][r]), fmaxf(s[2][r], s[3][r]));
        pm = fmaxf(pm, __shfl_xor(pm, 1, 16));
        pm = fmaxf(pm, __shfl_xor(pm, 2, 16));
        pm = fmaxf(pm, __shfl_xor(pm, 4, 16));
        pm = fmaxf(pm, __shfl_xor(pm, 8, 16));
        pmax[r] = pm;
      }
      bool need = false;
#pragma unroll
      for (int r = 0; r < 4; ++r) need |= (pmax[r] > mst[g][r]);
      if (__any(need)) {  // skip rescale pass when no row's max grew (exact)
#pragma unroll
        for (int r = 0; r < 4; ++r) {
          const float mnew = fmaxf(mst[g][r], pmax[r]);
          const float alpha = __builtin_amdgcn_exp2f(mst[g][r] - mnew);
          mst[g][r] = mnew;
          lst[g][r] *= alpha;
#pragma unroll
          for (int n = 0; n < 8; ++n) o[g][n][r] *= alpha;
        }
      }
      float rsum[4] = {0.f, 0.f, 0.f, 0.f};
#pragma unroll
      for (int j = 0; j < 4; ++j)
#pragma unroll
        for (int r = 0; r < 4; ++r) {
          const float p = __builtin_amdgcn_exp2f(s[j][r] - mst[g][r]);
          rsum[r] += p;
          Ps[w][lg * 4 + r][j * 16 + lr] = (bf16)p;
        }
#pragma unroll
      for (int r = 0; r < 4; ++r) {
        rsum[r] += __shfl_xor(rsum[r], 1, 16);
        rsum[r] += __shfl_xor(rsum[r], 2, 16);
        rsum[r] += __shfl_xor(rsum[r], 4, 16);
        rsum[r] += __shfl_xor(rsum[r], 8, 16);
        lst[g][r] += rsum[r];
      }

      // P (via per-wave LDS, within-wave ordering) @ V (swizzled read)
      bf16x8 pf[2];
#pragma unroll
      for (int kk = 0; kk < 2; ++kk)
        pf[kk] = *(const bf16x8*)&Ps[w][lr][kk * 32 + lg * 8];
      __builtin_amdgcn_s_setprio(1);
#pragma unroll
      for (int n = 0; n < 8; ++n)
#pragma unroll
        for (int kk = 0; kk < 2; ++kk) {
          const bf16x8 vf = *(const bf16x8*)&Vc[(n * 16 + lr) * 64 +
                                               ((kk * 32 + lg * 8) ^ rswz)];
          o[g][n] = __builtin_amdgcn_mfma_f32_16x16x32_bf16(pf[kk], vf,
                                                            o[g][n], 0, 0, 0);
        }
      __builtin_amdgcn_s_setprio(0);
    }
    __builtin_amdgcn_sched_barrier(0);
    __builtin_amdgcn_s_barrier();  // all reads of buf cur done before next
    __builtin_amdgcn_sched_barrier(0);  // STAGE overwrites it
  }

  // write attn-out as bf16 [B*T][C]
  const int b = bh >> 4, h = bh & 15;
#pragma unroll
  for (int g = 0; g < 2; ++g)
#pragma unroll
    for (int r = 0; r < 4; ++r) {
      const float inv = 1.0f / lst[g][r];
      const int t = q0 + g * 64 + wq * 16 + lg * 4 + r;
      bf16* dst = ob + ((size_t)(b * 2048 + t)) * 2048 + h * 128;
#pragma unroll
      for (int n = 0; n < 8; ++n) dst[n * 16 + lr] = (bf16)(o[g][n][r] * inv);
    }
}

// ---------------------------------------------------------------------------
extern "C" void kernel_launch(void* const* d_in, const int* in_sizes, int n_in,
                              void* d_out, int out_size, void* d_ws,
                              size_t ws_size, hipStream_t stream) {
  const float* x = (const float*)d_in[0];      // [4,2048,2048]
  const float* Wqkv = (const float*)d_in[1];   // [2048,6144]
  const float* bqkv = (const float*)d_in[2];   // [6144]
  const float* Wproj = (const float*)d_in[3];  // [2048,2048]
  const float* bproj = (const float*)d_in[4];  // [2048]
  float* out = (float*)d_out;                  // [8192,2048] fp32

  char* ws = (char*)d_ws;  // needs ~192 MiB
  bf16* xb     = (bf16*)(ws);                  // 33554432 B  x bf16
  bf16* wqkvT  = (bf16*)(ws + 33554432);       // 25165824 B  Wqkv^T
  bf16* wprojT = (bf16*)(ws + 58720256);       //  8388608 B  Wproj^T
  bf16* qb     = (bf16*)(ws + 67108864);       // 33554432 B  Q [BH][T][D]
  bf16* kb     = (bf16*)(ws + 100663296);      // 33554432 B  K [BH][T][D]
  bf16* vtb    = (bf16*)(ws + 134217728);      // 33554432 B  V^T [BH][D][T]
  bf16* ab     = (bf16*)(ws + 167772160);      // 33554432 B  attn out bf16

  cast_f32_bf16<<<8192, 256, 0, stream>>>(x, xb, 2097152);
  transpose_cast<<<dim3(192, 64), 256, 0, stream>>>(Wqkv, wqkvT, 2048, 6144);
  transpose_cast<<<dim3(64, 64), 256, 0, stream>>>(Wproj, wprojT, 2048, 2048);
  gemm256<0><<<768, 512, 0, stream>>>(xb, wqkvT, bqkv, 8192, 6144, 2048,
                                      nullptr, qb, kb, vtb);
  attn_kernel<<<dim3(8, 64), 512, 0, stream>>>(qb, kb, vtb, ab);
  gemm256<1><<<256, 512, 0, stream>>>(ab, wprojT, bproj, 8192, 2048, 2048,
                                      out, nullptr, nullptr, nullptr);
}